// Round 1
// baseline (1441.677 us; speedup 1.0000x reference)
//
#include <hip/hip_runtime.h>
#include <math.h>

// ---------------------------------------------------------------------------
// KGMC SAGE: 4x SAGEConv(mean) + tanh over (N=200k, E=3.2M, d=32), then a
// 4096-pair MLP head. Strategy:
//   1. Build CSR keyed by dst (storing src) once per call: histogram ->
//      single-block scan -> scatter-fill. Avoids per-layer float atomics.
//   2. Per layer: fused gather-mean + dual 32x32 GEMM + tanh. One 32-lane
//      group per node (lane = feature). Output written directly into the
//      layer's 32-col slice of concat_states (stride 128) in d_out.
//   3. Pair MLP: 8 pairs/block, W1 reads amortized 8x via registers.
// ---------------------------------------------------------------------------

__global__ void hist_kernel(const int* __restrict__ dst, int* __restrict__ degi, int E) {
    int t = blockIdx.x * blockDim.x + threadIdx.x;
    if (t < E) atomicAdd(&degi[dst[t]], 1);
}

__global__ void scan_kernel(const int* __restrict__ degi, int* __restrict__ rowstart,
                            int* __restrict__ cursor, int N, int E) {
    __shared__ int sums[1024];
    int t = threadIdx.x;
    int chunk = (N + 1023) >> 10;
    int base = t * chunk;
    int end  = min(base + chunk, N);
    int s = 0;
    for (int i = base; i < end; ++i) s += degi[i];
    sums[t] = s;
    __syncthreads();
    // Hillis-Steele inclusive scan over 1024 partials
    for (int off = 1; off < 1024; off <<= 1) {
        int v = (t >= off) ? sums[t - off] : 0;
        __syncthreads();
        sums[t] += v;
        __syncthreads();
    }
    int run = (t > 0) ? sums[t - 1] : 0;
    for (int i = base; i < end; ++i) {
        rowstart[i] = run;
        cursor[i]   = run;
        run += degi[i];
    }
    if (t == 0) rowstart[N] = E;
}

__global__ void fill_kernel(const int* __restrict__ src, const int* __restrict__ dst,
                            int* __restrict__ cursor, int* __restrict__ csr, int E) {
    int t = blockIdx.x * blockDim.x + threadIdx.x;
    if (t < E) {
        int d = dst[t];
        int p = atomicAdd(&cursor[d], 1);
        csr[p] = src[t];
    }
}

// Fused SAGE layer: mean-aggregate in-neighbors + h@Ws + mean@Wn + b, tanh.
// GROUPS node-groups of 32 lanes per block; lane index = output feature.
template <int GROUPS>
__global__ __launch_bounds__(GROUPS * 32)
void sage_layer(const float* __restrict__ h_in, int in_stride, int in_off,
                float* __restrict__ h_out, int out_stride, int out_off,
                const int* __restrict__ rowstart, const int* __restrict__ csr,
                const float* __restrict__ Ws, const float* __restrict__ Wn,
                const float* __restrict__ b, int N) {
    __shared__ float2 WS[32 * 32];       // interleaved (Ws, Wn): one b64 read/k
    __shared__ float2 HM[GROUPS][32];    // per-group (h, mean) row
    __shared__ float  bS[32];

    int tid = threadIdx.x;
    for (int i = tid; i < 1024; i += GROUPS * 32)
        WS[i] = make_float2(Ws[i], Wn[i]);
    if (tid < 32) bS[tid] = b[tid];
    __syncthreads();

    int g = tid >> 5;
    int f = tid & 31;
    int n = blockIdx.x * GROUPS + g;
    if (n >= N) return;

    float hval = h_in[(size_t)n * in_stride + in_off + f];

    int start = rowstart[n];
    int end   = rowstart[n + 1];
    float acc = 0.f;
    int j = start;
    for (; j + 3 < end; j += 4) {
        int s0 = csr[j], s1 = csr[j + 1], s2 = csr[j + 2], s3 = csr[j + 3];
        float a0 = h_in[(size_t)s0 * in_stride + in_off + f];
        float a1 = h_in[(size_t)s1 * in_stride + in_off + f];
        float a2 = h_in[(size_t)s2 * in_stride + in_off + f];
        float a3 = h_in[(size_t)s3 * in_stride + in_off + f];
        acc += (a0 + a1) + (a2 + a3);
    }
    for (; j < end; ++j)
        acc += h_in[(size_t)csr[j] * in_stride + in_off + f];

    int deg = end - start;
    float mval = acc / (float)(deg > 0 ? deg : 1);

    // share (h, mean) within the 32-lane group via LDS (same wave: issue-order
    // guarantees the write lands before the later reads; barrier pins codegen)
    HM[g][f] = make_float2(hval, mval);
    __builtin_amdgcn_wave_barrier();

    float out = bS[f];
#pragma unroll
    for (int k = 0; k < 32; ++k) {
        float2 hm = HM[g][k];            // broadcast
        float2 w  = WS[k * 32 + f];      // conflict-free (8B stride, 2-way free)
        out += hm.x * w.x + hm.y * w.y;
    }
    h_out[(size_t)n * out_stride + out_off + f] = tanhf(out);
}

// Pair MLP head: hdn = relu([cs[u], cs[i]] @ W1 + bl1); out = sigmoid(hdn@W2+bl2)
template <int PPB>
__global__ __launch_bounds__(128)
void pair_mlp(const float* __restrict__ cs, const int* __restrict__ uidx,
              const int* __restrict__ iidx, const float* __restrict__ W1,
              const float* __restrict__ bl1, const float* __restrict__ W2,
              const float* __restrict__ bl2, float* __restrict__ score, int P) {
    __shared__ float sp[PPB][256];
    __shared__ float wsum[2][PPB];
    int j  = threadIdx.x;                // 0..127 (hidden unit)
    int p0 = blockIdx.x * PPB;

    for (int q = 0; q < PPB; ++q) {
        int p = p0 + q;
        if (p < P) {
            int u  = uidx[p];
            int it = iidx[p];
            sp[q][j]       = cs[(size_t)u  * 128 + j];
            sp[q][128 + j] = cs[(size_t)it * 128 + j];
        } else {
            sp[q][j] = 0.f;
            sp[q][128 + j] = 0.f;
        }
    }
    __syncthreads();

    float acc[PPB];
    float bb = bl1[j];
#pragma unroll
    for (int q = 0; q < PPB; ++q) acc[q] = bb;

    for (int i = 0; i < 256; ++i) {
        float w = W1[i * 128 + j];       // coalesced, L2-resident
#pragma unroll
        for (int q = 0; q < PPB; ++q) acc[q] += sp[q][i] * w;
    }

    float w2   = W2[j];
    int   wave = j >> 6;
    int   lane = j & 63;
#pragma unroll
    for (int q = 0; q < PPB; ++q) {
        float v = fmaxf(acc[q], 0.f) * w2;
#pragma unroll
        for (int o = 32; o > 0; o >>= 1) v += __shfl_xor(v, o, 64);
        if (lane == 0) wsum[wave][q] = v;
    }
    __syncthreads();
    if (j < PPB) {
        int p = p0 + j;
        if (p < P) {
            float t = wsum[0][j] + wsum[1][j] + bl2[0];
            score[p] = 1.f / (1.f + expf(-t));
        }
    }
}

extern "C" void kernel_launch(void* const* d_in, const int* in_sizes, int n_in,
                              void* d_out, int out_size, void* d_ws, size_t ws_size,
                              hipStream_t stream) {
    const float* x    = (const float*)d_in[0];
    const int*   src  = (const int*)d_in[1];
    const int*   dst  = (const int*)d_in[2];
    const int*   uidx = (const int*)d_in[3];
    const int*   iidx = (const int*)d_in[4];
    const float* Ws[4] = {(const float*)d_in[5], (const float*)d_in[8],
                          (const float*)d_in[11], (const float*)d_in[14]};
    const float* Wn[4] = {(const float*)d_in[6], (const float*)d_in[9],
                          (const float*)d_in[12], (const float*)d_in[15]};
    const float* bb[4] = {(const float*)d_in[7], (const float*)d_in[10],
                          (const float*)d_in[13], (const float*)d_in[16]};
    const float* W1  = (const float*)d_in[17];
    const float* bl1 = (const float*)d_in[18];
    const float* W2  = (const float*)d_in[19];
    const float* bl2 = (const float*)d_in[20];

    const int N = in_sizes[0] / 32;
    const int E = in_sizes[1];
    const int P = in_sizes[3];

    // workspace layout (ints), 256B-aligned chunks
    int* ws_i     = (int*)d_ws;
    size_t o      = 0;
    int* degi     = ws_i + o; o += (size_t)((N + 63) & ~63);
    int* rowstart = ws_i + o; o += (size_t)((N + 1 + 63) & ~63);
    int* cursor   = ws_i + o; o += (size_t)((N + 63) & ~63);
    int* csr      = ws_i + o; o += (size_t)E;

    float* score = (float*)d_out;
    float* cs    = score + P;            // concat_states [N,128]

    // --- build CSR (dst -> list of src) ---
    hipMemsetAsync(degi, 0, sizeof(int) * N, stream);
    hist_kernel<<<(E + 255) / 256, 256, 0, stream>>>(dst, degi, E);
    scan_kernel<<<1, 1024, 0, stream>>>(degi, rowstart, cursor, N, E);
    fill_kernel<<<(E + 255) / 256, 256, 0, stream>>>(src, dst, cursor, csr, E);

    // --- 4 fused SAGE layers, writing concat_states slices ---
    sage_layer<8><<<(N + 7) / 8, 256, 0, stream>>>(
        x, 32, 0, cs, 128, 0, rowstart, csr, Ws[0], Wn[0], bb[0], N);
    for (int l = 1; l < 4; ++l) {
        sage_layer<8><<<(N + 7) / 8, 256, 0, stream>>>(
            cs, 128, (l - 1) * 32, cs, 128, l * 32, rowstart, csr,
            Ws[l], Wn[l], bb[l], N);
    }

    // --- pair MLP head ---
    pair_mlp<8><<<(P + 7) / 8, 128, 0, stream>>>(
        cs, uidx, iidx, W1, bl1, W2, bl2, score, P);
}

// Round 2
// 997.336 us; speedup vs baseline: 1.4455x; 1.4455x over previous
//
#include <hip/hip_runtime.h>
#include <math.h>

// ---------------------------------------------------------------------------
// KGMC SAGE: 4x SAGEConv(mean) + tanh over (N=200k, E=3.2M, d=32), then a
// 4096-pair MLP head.
//   1. Build CSR keyed by dst (storing src) once per call: histogram ->
//      3-kernel parallel scan -> scatter-fill. (R1: single-block scan was
//      460us = 32% of total; now ~98-block two-level scan.)
//   2. Per layer: fused gather-mean + dual 32x32 GEMM + tanh. One 32-lane
//      group per node (lane = feature). Output written directly into the
//      layer's 32-col slice of concat_states (stride 128) in d_out.
//   3. Pair MLP: 8 pairs/block, W1 reads amortized 8x via registers.
// ---------------------------------------------------------------------------

__global__ void hist_kernel(const int* __restrict__ dst, int* __restrict__ degi, int E) {
    int t = blockIdx.x * blockDim.x + threadIdx.x;
    if (t < E) atomicAdd(&degi[dst[t]], 1);
}

// ---- two-level parallel exclusive scan over degi[0..N) ----
constexpr int SCAN_T = 256;          // threads per scan block
constexpr int SCAN_V = 8;            // elems per thread
constexpr int SCAN_CHUNK = SCAN_T * SCAN_V;   // 2048

__global__ __launch_bounds__(SCAN_T)
void scan_partial(const int* __restrict__ degi, int* __restrict__ blocksum, int N) {
    int b = blockIdx.x, t = threadIdx.x;
    int base = b * SCAN_CHUNK + t * SCAN_V;
    int s = 0;
#pragma unroll
    for (int i = 0; i < SCAN_V; ++i) {
        int idx = base + i;
        if (idx < N) s += degi[idx];
    }
    __shared__ int red[SCAN_T / 64];
#pragma unroll
    for (int o = 32; o > 0; o >>= 1) s += __shfl_xor(s, o, 64);
    if ((t & 63) == 0) red[t >> 6] = s;
    __syncthreads();
    if (t == 0) {
        int tot = 0;
#pragma unroll
        for (int w = 0; w < SCAN_T / 64; ++w) tot += red[w];
        blocksum[b] = tot;
    }
}

__global__ __launch_bounds__(1024)
void scan_blocksums(int* __restrict__ blocksum, int nb) {
    __shared__ int sh[1024];
    int t = threadIdx.x;
    int v = (t < nb) ? blocksum[t] : 0;
    sh[t] = v;
    __syncthreads();
    for (int off = 1; off < 1024; off <<= 1) {
        int u = (t >= off) ? sh[t - off] : 0;
        __syncthreads();
        sh[t] += u;
        __syncthreads();
    }
    if (t < nb) blocksum[t] = sh[t] - v;   // exclusive prefix
}

__global__ __launch_bounds__(SCAN_T)
void scan_emit(const int* __restrict__ degi, const int* __restrict__ blocksum,
               int* __restrict__ rowstart, int* __restrict__ cursor, int N, int E) {
    int b = blockIdx.x, t = threadIdx.x;
    int base = b * SCAN_CHUNK + t * SCAN_V;
    int v[SCAN_V];
    int s = 0;
#pragma unroll
    for (int i = 0; i < SCAN_V; ++i) {
        int idx = base + i;
        v[i] = (idx < N) ? degi[idx] : 0;
        s += v[i];
    }
    __shared__ int sh[SCAN_T];
    sh[t] = s;
    __syncthreads();
    for (int off = 1; off < SCAN_T; off <<= 1) {
        int u = (t >= off) ? sh[t - off] : 0;
        __syncthreads();
        sh[t] += u;
        __syncthreads();
    }
    int run = blocksum[b] + sh[t] - s;    // block offset + exclusive within block
#pragma unroll
    for (int i = 0; i < SCAN_V; ++i) {
        int idx = base + i;
        if (idx < N) {
            rowstart[idx] = run;
            cursor[idx]   = run;
            run += v[i];
        }
    }
    if (b == 0 && t == 0) rowstart[N] = E;
}

__global__ void fill_kernel(const int* __restrict__ src, const int* __restrict__ dst,
                            int* __restrict__ cursor, int* __restrict__ csr, int E) {
    int t = blockIdx.x * blockDim.x + threadIdx.x;
    if (t < E) {
        int d = dst[t];
        int p = atomicAdd(&cursor[d], 1);
        csr[p] = src[t];
    }
}

// Fused SAGE layer: mean-aggregate in-neighbors + h@Ws + mean@Wn + b, tanh.
// GROUPS node-groups of 32 lanes per block; lane index = output feature.
template <int GROUPS>
__global__ __launch_bounds__(GROUPS * 32)
void sage_layer(const float* __restrict__ h_in, int in_stride, int in_off,
                float* __restrict__ h_out, int out_stride, int out_off,
                const int* __restrict__ rowstart, const int* __restrict__ csr,
                const float* __restrict__ Ws, const float* __restrict__ Wn,
                const float* __restrict__ b, int N) {
    __shared__ float2 WS[32 * 32];       // interleaved (Ws, Wn): one b64 read/k
    __shared__ float2 HM[GROUPS][32];    // per-group (h, mean) row
    __shared__ float  bS[32];

    int tid = threadIdx.x;
    for (int i = tid; i < 1024; i += GROUPS * 32)
        WS[i] = make_float2(Ws[i], Wn[i]);
    if (tid < 32) bS[tid] = b[tid];
    __syncthreads();

    int g = tid >> 5;
    int f = tid & 31;
    int n = blockIdx.x * GROUPS + g;
    if (n >= N) return;

    float hval = h_in[(size_t)n * in_stride + in_off + f];

    int start = rowstart[n];
    int end   = rowstart[n + 1];
    float acc = 0.f;
    int j = start;
    for (; j + 3 < end; j += 4) {
        int s0 = csr[j], s1 = csr[j + 1], s2 = csr[j + 2], s3 = csr[j + 3];
        float a0 = h_in[(size_t)s0 * in_stride + in_off + f];
        float a1 = h_in[(size_t)s1 * in_stride + in_off + f];
        float a2 = h_in[(size_t)s2 * in_stride + in_off + f];
        float a3 = h_in[(size_t)s3 * in_stride + in_off + f];
        acc += (a0 + a1) + (a2 + a3);
    }
    for (; j < end; ++j)
        acc += h_in[(size_t)csr[j] * in_stride + in_off + f];

    int deg = end - start;
    float mval = acc / (float)(deg > 0 ? deg : 1);

    // share (h, mean) within the 32-lane group via LDS (same wave: issue-order
    // guarantees the write lands before the later reads; barrier pins codegen)
    HM[g][f] = make_float2(hval, mval);
    __builtin_amdgcn_wave_barrier();

    float out = bS[f];
#pragma unroll
    for (int k = 0; k < 32; ++k) {
        float2 hm = HM[g][k];            // broadcast
        float2 w  = WS[k * 32 + f];      // conflict-free (8B stride, 2-way free)
        out += hm.x * w.x + hm.y * w.y;
    }
    h_out[(size_t)n * out_stride + out_off + f] = tanhf(out);
}

// Pair MLP head: hdn = relu([cs[u], cs[i]] @ W1 + bl1); out = sigmoid(hdn@W2+bl2)
template <int PPB>
__global__ __launch_bounds__(128)
void pair_mlp(const float* __restrict__ cs, const int* __restrict__ uidx,
              const int* __restrict__ iidx, const float* __restrict__ W1,
              const float* __restrict__ bl1, const float* __restrict__ W2,
              const float* __restrict__ bl2, float* __restrict__ score, int P) {
    __shared__ float sp[PPB][256];
    __shared__ float wsum[2][PPB];
    int j  = threadIdx.x;                // 0..127 (hidden unit)
    int p0 = blockIdx.x * PPB;

    for (int q = 0; q < PPB; ++q) {
        int p = p0 + q;
        if (p < P) {
            int u  = uidx[p];
            int it = iidx[p];
            sp[q][j]       = cs[(size_t)u  * 128 + j];
            sp[q][128 + j] = cs[(size_t)it * 128 + j];
        } else {
            sp[q][j] = 0.f;
            sp[q][128 + j] = 0.f;
        }
    }
    __syncthreads();

    float acc[PPB];
    float bb = bl1[j];
#pragma unroll
    for (int q = 0; q < PPB; ++q) acc[q] = bb;

    for (int i = 0; i < 256; ++i) {
        float w = W1[i * 128 + j];       // coalesced, L2-resident
#pragma unroll
        for (int q = 0; q < PPB; ++q) acc[q] += sp[q][i] * w;
    }

    float w2   = W2[j];
    int   wave = j >> 6;
    int   lane = j & 63;
#pragma unroll
    for (int q = 0; q < PPB; ++q) {
        float v = fmaxf(acc[q], 0.f) * w2;
#pragma unroll
        for (int o = 32; o > 0; o >>= 1) v += __shfl_xor(v, o, 64);
        if (lane == 0) wsum[wave][q] = v;
    }
    __syncthreads();
    if (j < PPB) {
        int p = p0 + j;
        if (p < P) {
            float t = wsum[0][j] + wsum[1][j] + bl2[0];
            score[p] = 1.f / (1.f + expf(-t));
        }
    }
}

extern "C" void kernel_launch(void* const* d_in, const int* in_sizes, int n_in,
                              void* d_out, int out_size, void* d_ws, size_t ws_size,
                              hipStream_t stream) {
    const float* x    = (const float*)d_in[0];
    const int*   src  = (const int*)d_in[1];
    const int*   dst  = (const int*)d_in[2];
    const int*   uidx = (const int*)d_in[3];
    const int*   iidx = (const int*)d_in[4];
    const float* Ws[4] = {(const float*)d_in[5], (const float*)d_in[8],
                          (const float*)d_in[11], (const float*)d_in[14]};
    const float* Wn[4] = {(const float*)d_in[6], (const float*)d_in[9],
                          (const float*)d_in[12], (const float*)d_in[15]};
    const float* bb[4] = {(const float*)d_in[7], (const float*)d_in[10],
                          (const float*)d_in[13], (const float*)d_in[16]};
    const float* W1  = (const float*)d_in[17];
    const float* bl1 = (const float*)d_in[18];
    const float* W2  = (const float*)d_in[19];
    const float* bl2 = (const float*)d_in[20];

    const int N = in_sizes[0] / 32;
    const int E = in_sizes[1];
    const int P = in_sizes[3];
    const int NB = (N + SCAN_CHUNK - 1) / SCAN_CHUNK;   // 98 for N=200k

    // workspace layout (ints), 64-elem aligned chunks
    int* ws_i     = (int*)d_ws;
    size_t o      = 0;
    int* degi     = ws_i + o; o += (size_t)((N + 63) & ~63);
    int* rowstart = ws_i + o; o += (size_t)((N + 1 + 63) & ~63);
    int* cursor   = ws_i + o; o += (size_t)((N + 63) & ~63);
    int* blocksum = ws_i + o; o += (size_t)((NB + 63) & ~63);
    int* csr      = ws_i + o; o += (size_t)E;

    float* score = (float*)d_out;
    float* cs    = score + P;            // concat_states [N,128]

    // --- build CSR (dst -> list of src) ---
    hipMemsetAsync(degi, 0, sizeof(int) * N, stream);
    hist_kernel<<<(E + 255) / 256, 256, 0, stream>>>(dst, degi, E);
    scan_partial<<<NB, SCAN_T, 0, stream>>>(degi, blocksum, N);
    scan_blocksums<<<1, 1024, 0, stream>>>(blocksum, NB);
    scan_emit<<<NB, SCAN_T, 0, stream>>>(degi, blocksum, rowstart, cursor, N, E);
    fill_kernel<<<(E + 255) / 256, 256, 0, stream>>>(src, dst, cursor, csr, E);

    // --- 4 fused SAGE layers, writing concat_states slices ---
    sage_layer<8><<<(N + 7) / 8, 256, 0, stream>>>(
        x, 32, 0, cs, 128, 0, rowstart, csr, Ws[0], Wn[0], bb[0], N);
    for (int l = 1; l < 4; ++l) {
        sage_layer<8><<<(N + 7) / 8, 256, 0, stream>>>(
            cs, 128, (l - 1) * 32, cs, 128, l * 32, rowstart, csr,
            Ws[l], Wn[l], bb[l], N);
    }

    // --- pair MLP head ---
    pair_mlp<8><<<(P + 7) / 8, 128, 0, stream>>>(
        cs, uidx, iidx, W1, bl1, W2, bl2, score, P);
}

// Round 3
// 711.673 us; speedup vs baseline: 2.0258x; 1.4014x over previous
//
#include <hip/hip_runtime.h>
#include <math.h>

// ---------------------------------------------------------------------------
// KGMC SAGE: 4x SAGEConv(mean) + tanh over (N=200k, E=3.2M, d=32), then a
// 4096-pair MLP head.
//   CSR build (R2): bucketed counting sort. R1's hist+fill did 6.4M global
//   atomics + random 4B scatters (WRITE_SIZE 203MB, 16x amplification).
//   Now: LDS histograms + bucket-grouped packed edges + per-bucket fine fill
//   where each block owns an L2-resident 32KB csr window (clean writebacks).
//   Packed edge array lives in the tail of d_out (overwritten by sage later).
//   Layers: fused gather-mean + dual 32x32 GEMM + tanh, one 32-lane group
//   per node, output written into the layer's 32-col slice of concat_states.
// ---------------------------------------------------------------------------

constexpr int BN       = 512;       // nodes per bucket
constexpr int LOG_BN   = 9;
constexpr int MAXBUCK  = 512;       // supports N <= 262144 (src fits 18 bits)
constexpr int EPB      = 8192;      // edges per coarse block
constexpr int SRC_BITS = 18;
constexpr int SRC_MASK = (1 << SRC_BITS) - 1;

__global__ __launch_bounds__(256)
void coarse_count(const int* __restrict__ dst, int* __restrict__ bucket_cnt,
                  int E, int nbuck) {
    __shared__ int h[MAXBUCK];
    int t = threadIdx.x;
    for (int i = t; i < nbuck; i += 256) h[i] = 0;
    __syncthreads();
    int base = blockIdx.x * EPB;
    int end  = min(base + EPB, E);
    for (int j = base + t; j < end; j += 256)
        atomicAdd(&h[dst[j] >> LOG_BN], 1);
    __syncthreads();
    for (int i = t; i < nbuck; i += 256)
        if (h[i]) atomicAdd(&bucket_cnt[i], h[i]);
}

__global__ __launch_bounds__(512)
void bucket_scan(const int* __restrict__ bucket_cnt, int* __restrict__ bucket_base,
                 int* __restrict__ bucket_cur, int nbuck, int E) {
    __shared__ int sh[512];
    int t = threadIdx.x;
    int v = (t < nbuck) ? bucket_cnt[t] : 0;
    sh[t] = v;
    __syncthreads();
    for (int off = 1; off < 512; off <<= 1) {
        int u = (t >= off) ? sh[t - off] : 0;
        __syncthreads();
        sh[t] += u;
        __syncthreads();
    }
    if (t < nbuck) {
        int base = sh[t] - v;
        bucket_base[t] = base;
        bucket_cur[t]  = base;
    }
    if (t == 0) bucket_base[nbuck] = E;
}

__global__ __launch_bounds__(256)
void coarse_scatter(const int* __restrict__ src, const int* __restrict__ dst,
                    int* __restrict__ bucket_cur, int* __restrict__ packed,
                    int E, int nbuck) {
    __shared__ int h[MAXBUCK];
    int t = threadIdx.x;
    for (int i = t; i < nbuck; i += 256) h[i] = 0;
    __syncthreads();
    int base = blockIdx.x * EPB;
    int end  = min(base + EPB, E);
    for (int j = base + t; j < end; j += 256)
        atomicAdd(&h[dst[j] >> LOG_BN], 1);
    __syncthreads();
    for (int i = t; i < nbuck; i += 256) {
        int c = h[i];
        if (c) h[i] = atomicAdd(&bucket_cur[i], c);   // reserve global run
    }
    __syncthreads();
    for (int j = base + t; j < end; j += 256) {
        int d  = dst[j];
        int bk = d >> LOG_BN;
        int p  = atomicAdd(&h[bk], 1);                // LDS cursor -> global pos
        packed[p] = ((d & (BN - 1)) << SRC_BITS) | src[j];
    }
}

// One block per bucket: per-node count+scan+cursors in LDS, csr writes land
// in this block's contiguous [bucket_base[b], bucket_base[b+1]) window.
__global__ __launch_bounds__(512)
void fine_fill(const int* __restrict__ packed, const int* __restrict__ bucket_base,
               int* __restrict__ rowstart, int* __restrict__ csr, int N, int E) {
    __shared__ int cnt[BN];
    __shared__ int cur[BN];
    __shared__ int sh[512];
    int b = blockIdx.x, t = threadIdx.x;
    int ebase = bucket_base[b], eend = bucket_base[b + 1];
    cnt[t] = 0;
    __syncthreads();
    for (int j = ebase + t; j < eend; j += 512)
        atomicAdd(&cnt[packed[j] >> SRC_BITS], 1);
    __syncthreads();
    int v = cnt[t];
    sh[t] = v;
    __syncthreads();
    for (int off = 1; off < 512; off <<= 1) {
        int u = (t >= off) ? sh[t - off] : 0;
        __syncthreads();
        sh[t] += u;
        __syncthreads();
    }
    int excl = sh[t] - v;
    int node = b * BN + t;
    if (node < N) rowstart[node] = ebase + excl;
    cur[t] = ebase + excl;
    __syncthreads();
    for (int j = ebase + t; j < eend; j += 512) {
        int pv = packed[j];
        int p  = atomicAdd(&cur[pv >> SRC_BITS], 1);
        csr[p] = pv & SRC_MASK;
    }
    if (b == 0 && t == 0) rowstart[N] = E;
}

// Fused SAGE layer: mean-aggregate in-neighbors + h@Ws + mean@Wn + b, tanh.
template <int GROUPS>
__global__ __launch_bounds__(GROUPS * 32)
void sage_layer(const float* __restrict__ h_in, int in_stride, int in_off,
                float* __restrict__ h_out, int out_stride, int out_off,
                const int* __restrict__ rowstart, const int* __restrict__ csr,
                const float* __restrict__ Ws, const float* __restrict__ Wn,
                const float* __restrict__ b, int N) {
    __shared__ float2 WS[32 * 32];
    __shared__ float2 HM[GROUPS][32];
    __shared__ float  bS[32];

    int tid = threadIdx.x;
    for (int i = tid; i < 1024; i += GROUPS * 32)
        WS[i] = make_float2(Ws[i], Wn[i]);
    if (tid < 32) bS[tid] = b[tid];
    __syncthreads();

    int g = tid >> 5;
    int f = tid & 31;
    int n = blockIdx.x * GROUPS + g;
    if (n >= N) return;

    float hval = h_in[(size_t)n * in_stride + in_off + f];

    int start = rowstart[n];
    int end   = rowstart[n + 1];
    float acc = 0.f;
    int j = start;
    for (; j + 3 < end; j += 4) {
        int s0 = csr[j], s1 = csr[j + 1], s2 = csr[j + 2], s3 = csr[j + 3];
        float a0 = h_in[(size_t)s0 * in_stride + in_off + f];
        float a1 = h_in[(size_t)s1 * in_stride + in_off + f];
        float a2 = h_in[(size_t)s2 * in_stride + in_off + f];
        float a3 = h_in[(size_t)s3 * in_stride + in_off + f];
        acc += (a0 + a1) + (a2 + a3);
    }
    for (; j < end; ++j)
        acc += h_in[(size_t)csr[j] * in_stride + in_off + f];

    int deg = end - start;
    float mval = acc / (float)(deg > 0 ? deg : 1);

    HM[g][f] = make_float2(hval, mval);
    __builtin_amdgcn_wave_barrier();

    float out = bS[f];
#pragma unroll
    for (int k = 0; k < 32; ++k) {
        float2 hm = HM[g][k];
        float2 w  = WS[k * 32 + f];
        out += hm.x * w.x + hm.y * w.y;
    }
    h_out[(size_t)n * out_stride + out_off + f] = tanhf(out);
}

// Pair MLP head: hdn = relu([cs[u], cs[i]] @ W1 + bl1); out = sigmoid(hdn@W2+bl2)
template <int PPB>
__global__ __launch_bounds__(128)
void pair_mlp(const float* __restrict__ cs, const int* __restrict__ uidx,
              const int* __restrict__ iidx, const float* __restrict__ W1,
              const float* __restrict__ bl1, const float* __restrict__ W2,
              const float* __restrict__ bl2, float* __restrict__ score, int P) {
    __shared__ float sp[PPB][256];
    __shared__ float wsum[2][PPB];
    int j  = threadIdx.x;
    int p0 = blockIdx.x * PPB;

    for (int q = 0; q < PPB; ++q) {
        int p = p0 + q;
        if (p < P) {
            int u  = uidx[p];
            int it = iidx[p];
            sp[q][j]       = cs[(size_t)u  * 128 + j];
            sp[q][128 + j] = cs[(size_t)it * 128 + j];
        } else {
            sp[q][j] = 0.f;
            sp[q][128 + j] = 0.f;
        }
    }
    __syncthreads();

    float acc[PPB];
    float bb = bl1[j];
#pragma unroll
    for (int q = 0; q < PPB; ++q) acc[q] = bb;

    for (int i = 0; i < 256; ++i) {
        float w = W1[i * 128 + j];
#pragma unroll
        for (int q = 0; q < PPB; ++q) acc[q] += sp[q][i] * w;
    }

    float w2   = W2[j];
    int   wave = j >> 6;
    int   lane = j & 63;
#pragma unroll
    for (int q = 0; q < PPB; ++q) {
        float v = fmaxf(acc[q], 0.f) * w2;
#pragma unroll
        for (int o = 32; o > 0; o >>= 1) v += __shfl_xor(v, o, 64);
        if (lane == 0) wsum[wave][q] = v;
    }
    __syncthreads();
    if (j < PPB) {
        int p = p0 + j;
        if (p < P) {
            float t = wsum[0][j] + wsum[1][j] + bl2[0];
            score[p] = 1.f / (1.f + expf(-t));
        }
    }
}

extern "C" void kernel_launch(void* const* d_in, const int* in_sizes, int n_in,
                              void* d_out, int out_size, void* d_ws, size_t ws_size,
                              hipStream_t stream) {
    const float* x    = (const float*)d_in[0];
    const int*   src  = (const int*)d_in[1];
    const int*   dst  = (const int*)d_in[2];
    const int*   uidx = (const int*)d_in[3];
    const int*   iidx = (const int*)d_in[4];
    const float* Ws[4] = {(const float*)d_in[5], (const float*)d_in[8],
                          (const float*)d_in[11], (const float*)d_in[14]};
    const float* Wn[4] = {(const float*)d_in[6], (const float*)d_in[9],
                          (const float*)d_in[12], (const float*)d_in[15]};
    const float* bb[4] = {(const float*)d_in[7], (const float*)d_in[10],
                          (const float*)d_in[13], (const float*)d_in[16]};
    const float* W1  = (const float*)d_in[17];
    const float* bl1 = (const float*)d_in[18];
    const float* W2  = (const float*)d_in[19];
    const float* bl2 = (const float*)d_in[20];

    const int N = in_sizes[0] / 32;
    const int E = in_sizes[1];
    const int P = in_sizes[3];
    const int NBUCK = (N + BN - 1) / BN;            // 391 for N=200k
    const int NEB   = (E + EPB - 1) / EPB;          // coarse blocks

    // workspace (ints)
    int* ws_i        = (int*)d_ws;
    size_t o         = 0;
    int* bucket_cnt  = ws_i + o; o += MAXBUCK;
    int* bucket_base = ws_i + o; o += MAXBUCK + 1;
    int* bucket_cur  = ws_i + o; o += MAXBUCK;
    int* rowstart    = ws_i + o; o += (size_t)((N + 1 + 63) & ~63);
    int* csr         = ws_i + o; o += (size_t)E;

    float* score = (float*)d_out;
    float* cs    = score + P;                       // concat_states [N,128]
    // packed edges live in the tail of d_out: used only during CSR build,
    // fully overwritten afterwards by the sage layers writing cs.
    int* packed  = (int*)d_out + ((size_t)out_size - E);

    // --- build CSR (dst -> list of src) via bucketed counting sort ---
    hipMemsetAsync(bucket_cnt, 0, sizeof(int) * MAXBUCK, stream);
    coarse_count<<<NEB, 256, 0, stream>>>(dst, bucket_cnt, E, NBUCK);
    bucket_scan<<<1, 512, 0, stream>>>(bucket_cnt, bucket_base, bucket_cur, NBUCK, E);
    coarse_scatter<<<NEB, 256, 0, stream>>>(src, dst, bucket_cur, packed, E, NBUCK);
    fine_fill<<<NBUCK, 512, 0, stream>>>(packed, bucket_base, rowstart, csr, N, E);

    // --- 4 fused SAGE layers, writing concat_states slices ---
    sage_layer<8><<<(N + 7) / 8, 256, 0, stream>>>(
        x, 32, 0, cs, 128, 0, rowstart, csr, Ws[0], Wn[0], bb[0], N);
    for (int l = 1; l < 4; ++l) {
        sage_layer<8><<<(N + 7) / 8, 256, 0, stream>>>(
            cs, 128, (l - 1) * 32, cs, 128, l * 32, rowstart, csr,
            Ws[l], Wn[l], bb[l], N);
    }

    // --- pair MLP head ---
    pair_mlp<8><<<(P + 7) / 8, 128, 0, stream>>>(
        cs, uidx, iidx, W1, bl1, W2, bl2, score, P);
}